// Round 9
// baseline (214.586 us; speedup 1.0000x reference)
//
#include <hip/hip_runtime.h>

#define S_LEN 2048
#define D_MODEL 1024
#define DH 64      // head dim
#define BQ 128     // q rows per block (32 per wave)
#define BK 128     // keys per k-tile
#define LDV 136    // padded LDS row stride for V (u16 elems)
#define ZSCALE 0.18033688f   // 0.125 * log2(e) — folded into Q fragments

using short8 = __attribute__((ext_vector_type(8))) short;
using s4v    = __attribute__((ext_vector_type(4))) short;
using f32x4  = __attribute__((ext_vector_type(4))) float;

__device__ __forceinline__ unsigned short f2bf(float x) {
    union { float f; unsigned int u; } c; c.f = x;
    unsigned int u = c.u;
    u += 0x7fffu + ((u >> 16) & 1u);   // RNE
    return (unsigned short)(u >> 16);
}

// ---- fused converter (verified) ----
// blocks [0,1024): V f32 -> bf16 transposed VT[(b*16+h)*64+d][s]
// blocks [1024,2048): mask int32 -> packed bits Mb[row][32] (u64 per 64 cols)
// blocks [2048,3072): K f32 -> bf16 KB   [only when grid=3072]
__global__ __launch_bounds__(256) void cvt_fused(const float* __restrict__ V,
                                                 const int* __restrict__ M,
                                                 const float* __restrict__ K,
                                                 unsigned short* __restrict__ VT,
                                                 unsigned long long* __restrict__ Mb,
                                                 unsigned short* __restrict__ KB) {
    const int blk = blockIdx.x;
    const int tid = threadIdx.x;
    if (blk < 1024) {
        __shared__ float tsF[64][65];
        const int b  = blk >> 9;
        const int h  = (blk >> 5) & 15;
        const int s0 = (blk & 31) * 64;
        #pragma unroll
        for (int it = 0; it < 2; ++it) {
            int seg = tid + it * 256;
            int s = seg >> 3, d8 = (seg & 7) << 3;
            const float* p = V + (size_t)(b * S_LEN + s0 + s) * D_MODEL + h * DH + d8;
            f32x4 a = *(const f32x4*)p;
            f32x4 c = *(const f32x4*)(p + 4);
            #pragma unroll
            for (int j = 0; j < 4; ++j) { tsF[s][d8 + j] = a[j]; tsF[s][d8 + 4 + j] = c[j]; }
        }
        __syncthreads();
        #pragma unroll
        for (int it = 0; it < 2; ++it) {
            int seg = tid + it * 256;
            int d = seg >> 3, s8 = (seg & 7) << 3;
            short8 w;
            #pragma unroll
            for (int j = 0; j < 8; ++j) w[j] = (short)f2bf(tsF[s8 + j][d]);
            *(short8*)(VT + ((size_t)((b * 16 + h) * 64 + d)) * S_LEN + s0 + s8) = w;
        }
    } else if (blk < 2048) {
        const int pb   = blk - 1024;
        const int wave = tid >> 6, lane = tid & 63;
        const int row  = pb * 4 + wave;
        const int* mp  = M + (size_t)row * S_LEN;
        #pragma unroll 4
        for (int it = 0; it < 32; ++it) {
            int m = mp[it * 64 + lane];
            unsigned long long bal = __ballot(m != 0);
            if (lane == 0) Mb[(size_t)row * 32 + it] = bal;
        }
    } else {
        size_t base = (size_t)(blk - 2048) * 4096;
        #pragma unroll
        for (int it = 0; it < 4; ++it) {
            size_t i = base + ((size_t)(it * 256 + tid)) * 4;
            f32x4 a = *(const f32x4*)(K + i);
            s4v w;
            #pragma unroll
            for (int j = 0; j < 4; ++j) w[j] = (short)f2bf(a[j]);
            *(s4v*)(KB + i) = w;
        }
    }
}

// ---- main kernel v12 = v11 minus the K-LDS apparatus:
//  * K fragments in REGISTERS, loaded straight from global with the v8-verified
//    kappa mapping; loads for tile t+1 issued right after the barrier (kf regs
//    are dead after QK[t]) so PV[t] (~700+ cyc) hides the L2 latency.
//  * V double-buffered in LDS -> ONE barrier per tile (between QK and PV).
//  * Softmax: Q pre-scaled, p = exp2(mfma out), mask = in-register nibble-
//    spread AND on packed bf16 P-fragments (v11, verified).
// kappa: QK block ct, A-row i holds key cst(ct) + 8*(i>>2) + (i&3), with
//   cst = 64*(ct>>2) + 32*((ct>>1)&1) + 4*(ct&1).  Then s[ct][r] at lane
//   (n16=q, quad) = key cst + 8*quad + r; packing (s[2kc],s[2kc+1]) -> Af[kc]
//   gives the PV A-fragment for keys [kc*32,kc*32+32) with IDENTITY k-slots.
__global__ __launch_bounds__(256) void mha_fwd_v12(
    const float* __restrict__ Q,
    const float* __restrict__ K,             // f32 (used when KB == 0)
    const unsigned short* __restrict__ KB,   // bf16 preconverted (may be null)
    const unsigned short* __restrict__ VT,   // bf16 pre-transposed [d][s]
    const unsigned long long* __restrict__ Mb, // packed mask u64, 32/row
    float* __restrict__ O,
    int kbf)
{
    __shared__ alignas(16) unsigned short Vt[2][DH][LDV];

    // XCD-chunked swizzle: nwg=512, 8 XCDs -> each XCD gets 64 contiguous blk
    const int blk0 = blockIdx.x;
    const int blk  = ((blk0 & 7) << 6) | (blk0 >> 3);

    const int b   = blk >> 8;
    const int h   = (blk >> 4) & 15;
    const int qbase = (blk & 15) * BQ;
    const int bh  = b * 16 + h;

    const int tid  = threadIdx.x;
    const int wave = tid >> 6;
    const int lane = tid & 63;
    const int n16  = lane & 15;
    const int quad = lane >> 4;
    const int bq   = quad << 3;                       // mask half-word shift
    const int lrow = ((n16 >> 2) << 3) | (n16 & 3);   // lane part of kappa

    // V staging: 256 thr cover 16 rows x 128 cols per round (4 rounds)
    const int vrow = tid >> 4, vc8 = (tid & 15) << 3;

    // Q fragments (B operand), PRE-SCALED by ZSCALE
    short8 qf[2][2];
    #pragma unroll
    for (int qg = 0; qg < 2; ++qg) {
        const size_t qoff = (size_t)(b * S_LEN + qbase + wave * 32 + qg * 16 + n16) * D_MODEL
                          + h * DH + quad * 8;
        f32x4 a0 = *(const f32x4*)(Q + qoff);
        f32x4 a1 = *(const f32x4*)(Q + qoff + 4);
        f32x4 a2 = *(const f32x4*)(Q + qoff + 32);
        f32x4 a3 = *(const f32x4*)(Q + qoff + 36);
        short8 q0, q1;
        #pragma unroll
        for (int j = 0; j < 4; ++j) {
            q0[j] = (short)f2bf(a0[j] * ZSCALE); q0[4 + j] = (short)f2bf(a1[j] * ZSCALE);
            q1[j] = (short)f2bf(a2[j] * ZSCALE); q1[4 + j] = (short)f2bf(a3[j] * ZSCALE);
        }
        qf[qg][0] = q0; qf[qg][1] = q1;
    }

    const short8 ones = {0x3F80,0x3F80,0x3F80,0x3F80,0x3F80,0x3F80,0x3F80,0x3F80}; // bf16 1.0

    f32x4 o[2][4], o4[2];
    #pragma unroll
    for (int qg = 0; qg < 2; ++qg) {
        #pragma unroll
        for (int dg = 0; dg < 4; ++dg) o[qg][dg] = f32x4{0.f,0.f,0.f,0.f};
        o4[qg] = f32x4{0.f,0.f,0.f,0.f};
    }

    const unsigned long long* mrow[2];
    #pragma unroll
    for (int qg = 0; qg < 2; ++qg)
        mrow[qg] = Mb + (size_t)(b * S_LEN + qbase + wave * 32 + qg * 16 + n16) * 32;

    const size_t kbase = (size_t)(b * S_LEN) * D_MODEL + h * DH;
    const size_t vbase = (size_t)(bh * 64) * S_LEN;

    // K fragment loader (kappa layout); loads tile starting at key row kt
    short8 kf[8][2];
    auto load_kf = [&](int kt) {
        #pragma unroll
        for (int ct = 0; ct < 8; ++ct) {
            const int cst  = ((ct >> 2) << 6) | (((ct >> 1) & 1) << 5) | ((ct & 1) << 2);
            const int crow = kt + cst + lrow;
            if (kbf) {
                const unsigned short* kp = KB + kbase + (size_t)crow * D_MODEL + quad * 8;
                kf[ct][0] = *(const short8*)kp;
                kf[ct][1] = *(const short8*)(kp + 32);
            } else {
                const float* kp = K + kbase + (size_t)crow * D_MODEL + quad * 8;
                f32x4 p0 = *(const f32x4*)kp,        p1 = *(const f32x4*)(kp + 4);
                f32x4 p2 = *(const f32x4*)(kp + 32), p3 = *(const f32x4*)(kp + 36);
                short8 w0, w1;
                #pragma unroll
                for (int j = 0; j < 4; ++j) {
                    w0[j] = (short)f2bf(p0[j]); w0[4 + j] = (short)f2bf(p1[j]);
                    w1[j] = (short)f2bf(p2[j]); w1[4 + j] = (short)f2bf(p3[j]);
                }
                kf[ct][0] = w0; kf[ct][1] = w1;
            }
        }
    };

    // ---- prologue: V tile 0, K fragments tile 0, mask words tile 0 ----
    short8 va[4];
    unsigned long long mw[2][2];
    #pragma unroll
    for (int i = 0; i < 4; ++i)   // VT is [d][s]: tile offset on the COLUMN
        va[i] = *(const short8*)(VT + vbase + (size_t)(vrow + 16 * i) * S_LEN + vc8);
    load_kf(0);
    #pragma unroll
    for (int qg = 0; qg < 2; ++qg) { mw[qg][0] = mrow[qg][0]; mw[qg][1] = mrow[qg][1]; }

    int p = 0;
    for (int kb = 0; kb < S_LEN; kb += BK, p ^= 1) {
        // stage V tile -> Vt[p] (safe: readers of buf p finished before the
        // PREVIOUS tile's barrier; vmcnt wait on va auto-inserted)
        #pragma unroll
        for (int i = 0; i < 4; ++i)
            *(short8*)&Vt[p][vrow + 16 * i][vc8] = va[i];

        // issue next tile's V + mask loads (consumed next iteration)
        const int kn = kb + BK;
        const bool more = kn < S_LEN;
        short8 nva[4];
        unsigned long long nmw[2][2];
        if (more) {
            #pragma unroll
            for (int i = 0; i < 4; ++i)
                nva[i] = *(const short8*)(VT + vbase + (size_t)(vrow + 16 * i) * S_LEN + kn + vc8);
            const int wi = kn >> 6;
            #pragma unroll
            for (int qg = 0; qg < 2; ++qg) { nmw[qg][0] = mrow[qg][wi]; nmw[qg][1] = mrow[qg][wi + 1]; }
        }

        // mask half-words, pre-shifted by quad
        unsigned int am[2][4];
        #pragma unroll
        for (int qg = 0; qg < 2; ++qg) {
            am[qg][0] = ((unsigned int)mw[qg][0]) >> bq;
            am[qg][1] = ((unsigned int)(mw[qg][0] >> 32)) >> bq;
            am[qg][2] = ((unsigned int)mw[qg][1]) >> bq;
            am[qg][3] = ((unsigned int)(mw[qg][1] >> 32)) >> bq;
        }

        // QK^T + softmax (K fragments already in regs from last tile's PV phase)
        union { unsigned int u[4]; short8 v; } Af[2][4];   // [qg][kc]
        __builtin_amdgcn_s_setprio(1);
        #pragma unroll
        for (int ct = 0; ct < 8; ++ct) {
            f32x4 sA = {0.f,0.f,0.f,0.f}, sB = sA;
            sA = __builtin_amdgcn_mfma_f32_16x16x32_bf16(kf[ct][0], qf[0][0], sA, 0, 0, 0);
            sA = __builtin_amdgcn_mfma_f32_16x16x32_bf16(kf[ct][1], qf[0][1], sA, 0, 0, 0);
            sB = __builtin_amdgcn_mfma_f32_16x16x32_bf16(kf[ct][0], qf[1][0], sB, 0, 0, 0);
            sB = __builtin_amdgcn_mfma_f32_16x16x32_bf16(kf[ct][1], qf[1][1], sB, 0, 0, 0);
            unsigned int puA[4], puB[4];
            #pragma unroll
            for (int r = 0; r < 4; ++r) {
                puA[r] = __float_as_uint(__builtin_amdgcn_exp2f(sA[r]));
                puB[r] = __float_as_uint(__builtin_amdgcn_exp2f(sB[r]));
            }
            const int sel = ct >> 1, sb = (ct & 1) * 4;
            unsigned int nibA = (am[0][sel] >> sb) & 0xFu;
            unsigned int nibB = (am[1][sel] >> sb) & 0xFu;
            unsigned int m8A = ((nibA * 0x00204081u) & 0x01010101u) * 0xFFu;
            unsigned int m8B = ((nibB * 0x00204081u) & 0x01010101u) * 0xFFu;
            const int kc = ct >> 1, ub = (ct & 1) * 2;
            Af[0][kc].u[ub + 0] = __builtin_amdgcn_perm(puA[1], puA[0], 0x07060302u)
                                & __builtin_amdgcn_perm(0u, m8A, 0x01010000u);
            Af[0][kc].u[ub + 1] = __builtin_amdgcn_perm(puA[3], puA[2], 0x07060302u)
                                & __builtin_amdgcn_perm(0u, m8A, 0x03030202u);
            Af[1][kc].u[ub + 0] = __builtin_amdgcn_perm(puB[1], puB[0], 0x07060302u)
                                & __builtin_amdgcn_perm(0u, m8B, 0x01010000u);
            Af[1][kc].u[ub + 1] = __builtin_amdgcn_perm(puB[3], puB[2], 0x07060302u)
                                & __builtin_amdgcn_perm(0u, m8B, 0x03030202u);
        }
        __builtin_amdgcn_s_setprio(0);

        // single barrier per tile: my V writes committed, all waves synced
        asm volatile("s_waitcnt lgkmcnt(0)" ::: "memory");
        __builtin_amdgcn_s_barrier();
        __builtin_amdgcn_sched_barrier(0);

        // reload kf with NEXT tile's fragments (kf regs dead after QK);
        // PV below (~700+ cyc) hides the L2 latency
        if (more) load_kf(kn);

        // PV + ones-column row sums (V from LDS, Af/ones in regs)
        __builtin_amdgcn_s_setprio(1);
        #pragma unroll
        for (int kc = 0; kc < 4; ++kc) {
            short8 v0 = *(const short8*)&Vt[p][      n16][kc * 32 + quad * 8];
            short8 v1 = *(const short8*)&Vt[p][16 + n16][kc * 32 + quad * 8];
            short8 v2 = *(const short8*)&Vt[p][32 + n16][kc * 32 + quad * 8];
            short8 v3 = *(const short8*)&Vt[p][48 + n16][kc * 32 + quad * 8];
            #pragma unroll
            for (int qg = 0; qg < 2; ++qg) {
                short8 af = Af[qg][kc].v;
                o[qg][0] = __builtin_amdgcn_mfma_f32_16x16x32_bf16(af, v0, o[qg][0], 0, 0, 0);
                o[qg][1] = __builtin_amdgcn_mfma_f32_16x16x32_bf16(af, v1, o[qg][1], 0, 0, 0);
                o[qg][2] = __builtin_amdgcn_mfma_f32_16x16x32_bf16(af, v2, o[qg][2], 0, 0, 0);
                o[qg][3] = __builtin_amdgcn_mfma_f32_16x16x32_bf16(af, v3, o[qg][3], 0, 0, 0);
                o4[qg]   = __builtin_amdgcn_mfma_f32_16x16x32_bf16(af, ones, o4[qg], 0, 0, 0);
            }
        }
        __builtin_amdgcn_s_setprio(0);

        if (more) {
            #pragma unroll
            for (int i = 0; i < 4; ++i) va[i] = nva[i];
            #pragma unroll
            for (int qg = 0; qg < 2; ++qg) { mw[qg][0] = nmw[qg][0]; mw[qg][1] = nmw[qg][1]; }
        }
    }

    // epilogue: normalize by MFMA row sums, store f32 (row=quad*4+r, col=n16)
    #pragma unroll
    for (int qg = 0; qg < 2; ++qg) {
        #pragma unroll
        for (int r = 0; r < 4; ++r) {
            float rl = 1.f / o4[qg][r];
            size_t row = (size_t)(b * S_LEN + qbase + wave * 32 + qg * 16 + quad * 4 + r);
            float* op = O + row * D_MODEL + h * DH + n16;
            op[0]  = o[qg][0][r] * rl;
            op[16] = o[qg][1][r] * rl;
            op[32] = o[qg][2][r] * rl;
            op[48] = o[qg][3][r] * rl;
        }
    }
}

extern "C" void kernel_launch(void* const* d_in, const int* in_sizes, int n_in,
                              void* d_out, int out_size, void* d_ws, size_t ws_size,
                              hipStream_t stream) {
    const float* Q = (const float*)d_in[0];
    const float* K = (const float*)d_in[1];
    const float* V = (const float*)d_in[2];
    const int*   M = (const int*)d_in[3];
    float*       O = (float*)d_out;

    const size_t NEL = (size_t)2 * S_LEN * D_MODEL;            // 4,194,304
    const size_t VT_BYTES = NEL * sizeof(unsigned short);      // 8 MB
    const size_t KB_BYTES = NEL * sizeof(unsigned short);      // 8 MB
    const size_t MB_BYTES = (size_t)2 * S_LEN * 32 * 8;        // 1 MB

    if (ws_size >= VT_BYTES + KB_BYTES + MB_BYTES) {           // 17 MB: full precompute
        unsigned short* VT = (unsigned short*)d_ws;
        unsigned short* KB = (unsigned short*)((char*)d_ws + VT_BYTES);
        unsigned long long* Mb = (unsigned long long*)((char*)d_ws + VT_BYTES + KB_BYTES);
        hipLaunchKernelGGL(cvt_fused, dim3(3072), dim3(256), 0, stream, V, M, K, VT, Mb, KB);
        hipLaunchKernelGGL(mha_fwd_v12, dim3(512), dim3(256), 0, stream,
                           Q, K, KB, VT, Mb, O, 1);
    } else {                                                   // 9 MB: inline K convert
        unsigned short* VT = (unsigned short*)d_ws;
        unsigned long long* Mb = (unsigned long long*)((char*)d_ws + VT_BYTES);
        hipLaunchKernelGGL(cvt_fused, dim3(2048), dim3(256), 0, stream, V, M, K, VT, Mb, (unsigned short*)0);
        hipLaunchKernelGGL(mha_fwd_v12, dim3(512), dim3(256), 0, stream,
                           Q, K, (const unsigned short*)0, VT, Mb, O, 0);
    }
}

// Round 10
// 188.536 us; speedup vs baseline: 1.1382x; 1.1382x over previous
//
#include <hip/hip_runtime.h>

#define S_LEN 2048
#define D_MODEL 1024
#define DH 64      // head dim
#define BQ 128     // q rows per block (32 per wave)
#define BK 128     // keys per k-tile
#define NT (S_LEN / BK)   // 16 tiles
#define LDK 72     // padded LDS row stride for K (u16 elems)
#define LDV 136    // padded LDS row stride for V (u16 elems)
#define ZSCALE 0.18033688f   // 0.125 * log2(e) — folded into Q fragments

using short8 = __attribute__((ext_vector_type(8))) short;
using s4v    = __attribute__((ext_vector_type(4))) short;
using f32x4  = __attribute__((ext_vector_type(4))) float;
using u32x4  = __attribute__((ext_vector_type(4))) unsigned int;

#define BMM(a, b, c) __builtin_amdgcn_mfma_f32_16x16x32_bf16((a), (b), (c), 0, 0, 0)

__device__ __forceinline__ unsigned short f2bf(float x) {
    union { float f; unsigned int u; } c; c.f = x;
    unsigned int u = c.u;
    u += 0x7fffu + ((u >> 16) & 1u);   // RNE
    return (unsigned short)(u >> 16);
}

// ---- fused converter (verified) ----
__global__ __launch_bounds__(256) void cvt_fused(const float* __restrict__ V,
                                                 const int* __restrict__ M,
                                                 const float* __restrict__ K,
                                                 unsigned short* __restrict__ VT,
                                                 unsigned long long* __restrict__ Mb,
                                                 unsigned short* __restrict__ KB) {
    const int blk = blockIdx.x;
    const int tid = threadIdx.x;
    if (blk < 1024) {
        __shared__ float tsF[64][65];
        const int b  = blk >> 9;
        const int h  = (blk >> 5) & 15;
        const int s0 = (blk & 31) * 64;
        #pragma unroll
        for (int it = 0; it < 2; ++it) {
            int seg = tid + it * 256;
            int s = seg >> 3, d8 = (seg & 7) << 3;
            const float* p = V + (size_t)(b * S_LEN + s0 + s) * D_MODEL + h * DH + d8;
            f32x4 a = *(const f32x4*)p;
            f32x4 c = *(const f32x4*)(p + 4);
            #pragma unroll
            for (int j = 0; j < 4; ++j) { tsF[s][d8 + j] = a[j]; tsF[s][d8 + 4 + j] = c[j]; }
        }
        __syncthreads();
        #pragma unroll
        for (int it = 0; it < 2; ++it) {
            int seg = tid + it * 256;
            int d = seg >> 3, s8 = (seg & 7) << 3;
            short8 w;
            #pragma unroll
            for (int j = 0; j < 8; ++j) w[j] = (short)f2bf(tsF[s8 + j][d]);
            *(short8*)(VT + ((size_t)((b * 16 + h) * 64 + d)) * S_LEN + s0 + s8) = w;
        }
    } else if (blk < 2048) {
        const int pb   = blk - 1024;
        const int wave = tid >> 6, lane = tid & 63;
        const int row  = pb * 4 + wave;
        const int* mp  = M + (size_t)row * S_LEN;
        #pragma unroll 4
        for (int it = 0; it < 32; ++it) {
            int m = mp[it * 64 + lane];
            unsigned long long bal = __ballot(m != 0);
            if (lane == 0) Mb[(size_t)row * 32 + it] = bal;
        }
    } else {
        size_t base = (size_t)(blk - 2048) * 4096;
        #pragma unroll
        for (int it = 0; it < 4; ++it) {
            size_t i = base + ((size_t)(it * 256 + tid)) * 4;
            f32x4 a = *(const f32x4*)(K + i);
            s4v w;
            #pragma unroll
            for (int j = 0; j < 4; ++j) w[j] = (short)f2bf(a[j]);
            *(s4v*)(KB + i) = w;
        }
    }
}

// ---- main kernel v13 = v11 numerics + cross-tile software pipeline:
//      QK[t] interleaved with PV[t-1] in ONE barrier-free compute region so
//      PV's MFMA/ds_read fill QK's exp2/perm stalls (the three pipes were
//      measured executing as a serial sum).  K and V double-buffered in LDS;
//      Af / prefetch-regs ping-pong between statically-named sets (rule #20).
__global__ __launch_bounds__(256) void mha_fwd_v13(
    const float* __restrict__ Q,
    const float* __restrict__ K,             // f32 (used when KB == 0)
    const unsigned short* __restrict__ KB,   // bf16 preconverted (may be null)
    const unsigned short* __restrict__ VT,   // bf16 pre-transposed [d][s]
    const unsigned long long* __restrict__ Mb, // packed mask u64, 32/row
    float* __restrict__ O,
    int kbf)
{
    __shared__ alignas(16) unsigned short Ks[2][BK][LDK];
    __shared__ alignas(16) unsigned short Vt[2][DH][LDV];

    // XCD-chunked swizzle: nwg=512, 8 XCDs -> each XCD gets 64 contiguous blk
    const int blk0 = blockIdx.x;
    const int blk  = ((blk0 & 7) << 6) | (blk0 >> 3);

    const int b   = blk >> 8;
    const int h   = (blk >> 4) & 15;
    const int qbase = (blk & 15) * BQ;
    const int bh  = b * 16 + h;

    const int tid  = threadIdx.x;
    const int wave = tid >> 6;
    const int lane = tid & 63;
    const int n16  = lane & 15;
    const int quad = lane >> 4;
    const int bq   = quad << 3;          // mask half-word shift

    // K staging: 256 thr cover 32 rows x 64 cols per round (4 rounds), sigma rows
    const int srow = tid >> 3, sc8 = (tid & 7) << 3;
    const int prow = (((srow >> 2) & 1) << 4) | (((srow >> 3) & 3) << 2) | (srow & 3);
    // V staging: 256 thr cover 16 rows x 128 cols per round (4 rounds)
    const int vrow = tid >> 4, vc8 = (tid & 15) << 3;

    // Q fragments (B operand), PRE-SCALED by ZSCALE
    short8 qf[2][2];
    #pragma unroll
    for (int qg = 0; qg < 2; ++qg) {
        const size_t qoff = (size_t)(b * S_LEN + qbase + wave * 32 + qg * 16 + n16) * D_MODEL
                          + h * DH + quad * 8;
        f32x4 a0 = *(const f32x4*)(Q + qoff);
        f32x4 a1 = *(const f32x4*)(Q + qoff + 4);
        f32x4 a2 = *(const f32x4*)(Q + qoff + 32);
        f32x4 a3 = *(const f32x4*)(Q + qoff + 36);
        short8 q0, q1;
        #pragma unroll
        for (int j = 0; j < 4; ++j) {
            q0[j] = (short)f2bf(a0[j] * ZSCALE); q0[4 + j] = (short)f2bf(a1[j] * ZSCALE);
            q1[j] = (short)f2bf(a2[j] * ZSCALE); q1[4 + j] = (short)f2bf(a3[j] * ZSCALE);
        }
        qf[qg][0] = q0; qf[qg][1] = q1;
    }

    const short8 ones = {0x3F80,0x3F80,0x3F80,0x3F80,0x3F80,0x3F80,0x3F80,0x3F80}; // bf16 1.0

    f32x4 o[2][4], o4[2];
    #pragma unroll
    for (int qg = 0; qg < 2; ++qg) {
        #pragma unroll
        for (int dg = 0; dg < 4; ++dg) o[qg][dg] = f32x4{0.f,0.f,0.f,0.f};
        o4[qg] = f32x4{0.f,0.f,0.f,0.f};
    }

    const unsigned long long* mrow[2];
    #pragma unroll
    for (int qg = 0; qg < 2; ++qg)
        mrow[qg] = Mb + (size_t)(b * S_LEN + qbase + wave * 32 + qg * 16 + n16) * 32;

    const size_t kbase = (size_t)(b * S_LEN) * D_MODEL + h * DH;
    const size_t vbase = (size_t)(bh * 64) * S_LEN;

    // ping-pong register state: even tiles in *A, odd tiles in *B
    short8 kaA[4], vaA[4], kaB[4], vaB[4];
    unsigned long long mwA[2][2], mwB[2][2];
    u32x4 AfA[2][4], AfB[2][4];

    auto LOADKV = [&](int kb2, short8 (&ka)[4], short8 (&va)[4]) {
        if (kb2 >= S_LEN) return;
        if (kbf) {
            #pragma unroll
            for (int i = 0; i < 4; ++i)
                ka[i] = *(const short8*)(KB + kbase + (size_t)(kb2 + i * 32 + srow) * D_MODEL + sc8);
        } else {
            #pragma unroll
            for (int i = 0; i < 4; ++i) {
                const float* kp = K + kbase + (size_t)(kb2 + i * 32 + srow) * D_MODEL + sc8;
                f32x4 p0 = *(const f32x4*)kp, p1 = *(const f32x4*)(kp + 4);
                short8 w;
                #pragma unroll
                for (int j = 0; j < 4; ++j) { w[j] = (short)f2bf(p0[j]); w[4 + j] = (short)f2bf(p1[j]); }
                ka[i] = w;
            }
        }
        #pragma unroll
        for (int i = 0; i < 4; ++i)   // VT is [d][s]: tile offset on the COLUMN
            va[i] = *(const short8*)(VT + vbase + (size_t)(vrow + 16 * i) * S_LEN + kb2 + vc8);
    };
    auto LOADM = [&](int kb2, unsigned long long (&mw)[2][2]) {
        if (kb2 >= S_LEN) return;
        const int wi = kb2 >> 6;
        #pragma unroll
        for (int qg = 0; qg < 2; ++qg) { mw[qg][0] = mrow[qg][wi]; mw[qg][1] = mrow[qg][wi + 1]; }
    };
    auto STAGE = [&](int pb, short8 (&ka)[4], short8 (&va)[4]) {
        #pragma unroll
        for (int i = 0; i < 4; ++i) {
            *(short8*)&Ks[pb][prow + 32 * i][sc8] = ka[i];
            *(short8*)&Vt[pb][vrow + 16 * i][vc8] = va[i];
        }
    };
    auto MKAM = [&](unsigned long long (&mw)[2][2], unsigned int (&am)[2][4]) {
        #pragma unroll
        for (int qg = 0; qg < 2; ++qg) {
            am[qg][0] = ((unsigned int)mw[qg][0]) >> bq;
            am[qg][1] = ((unsigned int)(mw[qg][0] >> 32)) >> bq;
            am[qg][2] = ((unsigned int)mw[qg][1]) >> bq;
            am[qg][3] = ((unsigned int)(mw[qg][1] >> 32)) >> bq;
        }
    };
    auto QKCT = [&](int pb, int ct, unsigned int (&am)[2][4], u32x4 (&Af)[2][4]) {
        short8 kf0 = *(const short8*)&Ks[pb][ct * 16 + n16][     quad * 8];
        short8 kf1 = *(const short8*)&Ks[pb][ct * 16 + n16][32 + quad * 8];
        f32x4 sA = {0.f,0.f,0.f,0.f}, sB = sA;
        sA = BMM(kf0, qf[0][0], sA); sA = BMM(kf1, qf[0][1], sA);
        sB = BMM(kf0, qf[1][0], sB); sB = BMM(kf1, qf[1][1], sB);
        unsigned int puA[4], puB[4];
        #pragma unroll
        for (int r = 0; r < 4; ++r) {
            puA[r] = __float_as_uint(__builtin_amdgcn_exp2f(sA[r]));
            puB[r] = __float_as_uint(__builtin_amdgcn_exp2f(sB[r]));
        }
        const int sel = ct >> 1, sb = (ct & 1) * 4, kc = ct >> 1, ub = (ct & 1) * 2;
        unsigned int nibA = (am[0][sel] >> sb) & 0xFu;
        unsigned int nibB = (am[1][sel] >> sb) & 0xFu;
        unsigned int m8A = ((nibA * 0x00204081u) & 0x01010101u) * 0xFFu;
        unsigned int m8B = ((nibB * 0x00204081u) & 0x01010101u) * 0xFFu;
        Af[0][kc][ub + 0] = __builtin_amdgcn_perm(puA[1], puA[0], 0x07060302u)
                          & __builtin_amdgcn_perm(0u, m8A, 0x01010000u);
        Af[0][kc][ub + 1] = __builtin_amdgcn_perm(puA[3], puA[2], 0x07060302u)
                          & __builtin_amdgcn_perm(0u, m8A, 0x03030202u);
        Af[1][kc][ub + 0] = __builtin_amdgcn_perm(puB[1], puB[0], 0x07060302u)
                          & __builtin_amdgcn_perm(0u, m8B, 0x01010000u);
        Af[1][kc][ub + 1] = __builtin_amdgcn_perm(puB[3], puB[2], 0x07060302u)
                          & __builtin_amdgcn_perm(0u, m8B, 0x03030202u);
    };
    auto PVKC = [&](int pb, int kc, u32x4 (&Af)[2][4]) {
        short8 v0 = *(const short8*)&Vt[pb][      n16][kc * 32 + quad * 8];
        short8 v1 = *(const short8*)&Vt[pb][16 + n16][kc * 32 + quad * 8];
        short8 v2 = *(const short8*)&Vt[pb][32 + n16][kc * 32 + quad * 8];
        short8 v3 = *(const short8*)&Vt[pb][48 + n16][kc * 32 + quad * 8];
        union { u32x4 u; short8 s; } c0, c1;
        c0.u = Af[0][kc]; c1.u = Af[1][kc];
        o[0][0] = BMM(c0.s, v0, o[0][0]); o[0][1] = BMM(c0.s, v1, o[0][1]);
        o[0][2] = BMM(c0.s, v2, o[0][2]); o[0][3] = BMM(c0.s, v3, o[0][3]);
        o4[0]   = BMM(c0.s, ones, o4[0]);
        o[1][0] = BMM(c1.s, v0, o[1][0]); o[1][1] = BMM(c1.s, v1, o[1][1]);
        o[1][2] = BMM(c1.s, v2, o[1][2]); o[1][3] = BMM(c1.s, v3, o[1][3]);
        o4[1]   = BMM(c1.s, ones, o4[1]);
    };
    // QK[t] on buffer qb interleaved with PV[t-1] on buffer vb (independent)
    auto COMPUTE = [&](int qb, int vb, unsigned int (&am)[2][4],
                       u32x4 (&AfC)[2][4], u32x4 (&AfP)[2][4], bool doPV) {
        __builtin_amdgcn_s_setprio(1);
        QKCT(qb, 0, am, AfC); QKCT(qb, 1, am, AfC); if (doPV) PVKC(vb, 0, AfP);
        QKCT(qb, 2, am, AfC); QKCT(qb, 3, am, AfC); if (doPV) PVKC(vb, 1, AfP);
        QKCT(qb, 4, am, AfC); QKCT(qb, 5, am, AfC); if (doPV) PVKC(vb, 2, AfP);
        QKCT(qb, 6, am, AfC); QKCT(qb, 7, am, AfC); if (doPV) PVKC(vb, 3, AfP);
        __builtin_amdgcn_s_setprio(0);
    };

    // ---- prologue: tile0 staged to buf0, tile1 in B-regs ----
    LOADKV(0, kaA, vaA); LOADM(0, mwA);
    STAGE(0, kaA, vaA);
    LOADKV(BK, kaB, vaB); LOADM(BK, mwB);
    asm volatile("s_waitcnt lgkmcnt(0)" ::: "memory");
    __builtin_amdgcn_s_barrier();
    __builtin_amdgcn_sched_barrier(0);

    // ---- t = 0 (peel): QK only -> AfA; stage tile1 -> buf1; load tile2 -> A ----
    {
        unsigned int am[2][4]; MKAM(mwA, am);
        COMPUTE(0, 0, am, AfA, AfB, false);
        LOADM(2 * BK, mwA);
        STAGE(1, kaB, vaB);                     // buf1 never read yet: no barrier needed
        LOADKV(2 * BK, kaA, vaA);
        asm volatile("s_waitcnt lgkmcnt(0)" ::: "memory");
        __builtin_amdgcn_s_barrier();
        __builtin_amdgcn_sched_barrier(0);
    }

    // ---- main: tiles t = 1..14 in statically-unrolled pairs ----
    for (int t = 1; t <= 13; t += 2) {
        {   // odd t: QK buf1 (mwB) -> AfB; PV[t-1] buf0 (AfA); stage tile t+1 -> buf0
            unsigned int am[2][4]; MKAM(mwB, am);
            COMPUTE(1, 0, am, AfB, AfA, true);
            LOADM((t + 2) * BK, mwB);
            __builtin_amdgcn_s_barrier();       // all waves done PV reads of buf0
            __builtin_amdgcn_sched_barrier(0);
            STAGE(0, kaA, vaA);                 // buf0 = tile t+1 (even -> from A)
            LOADKV((t + 2) * BK, kaB, vaB);     // tile t+2 (odd -> into B)
            asm volatile("s_waitcnt lgkmcnt(0)" ::: "memory");
            __builtin_amdgcn_s_barrier();
            __builtin_amdgcn_sched_barrier(0);
        }
        {   // even t+1: QK buf0 (mwA) -> AfA; PV[t] buf1 (AfB); stage tile t+2 -> buf1
            unsigned int am[2][4]; MKAM(mwA, am);
            COMPUTE(0, 1, am, AfA, AfB, true);
            LOADM((t + 3) * BK, mwA);
            __builtin_amdgcn_s_barrier();       // all waves done PV reads of buf1
            __builtin_amdgcn_sched_barrier(0);
            STAGE(1, kaB, vaB);                 // buf1 = tile t+2 (odd -> from B)
            LOADKV((t + 3) * BK, kaA, vaA);     // tile t+3 (even -> into A)
            asm volatile("s_waitcnt lgkmcnt(0)" ::: "memory");
            __builtin_amdgcn_s_barrier();
            __builtin_amdgcn_sched_barrier(0);
        }
    }

    // ---- epilogue t = 15: QK buf1 + PV[14] buf0, then PV[15] buf1 ----
    {
        unsigned int am[2][4]; MKAM(mwB, am);
        COMPUTE(1, 0, am, AfB, AfA, true);
        __builtin_amdgcn_s_setprio(1);
        PVKC(1, 0, AfB); PVKC(1, 1, AfB); PVKC(1, 2, AfB); PVKC(1, 3, AfB);
        __builtin_amdgcn_s_setprio(0);
    }

    // epilogue: normalize by MFMA row sums, store f32 (row=quad*4+r, col=n16)
    #pragma unroll
    for (int qg = 0; qg < 2; ++qg) {
        #pragma unroll
        for (int r = 0; r < 4; ++r) {
            float rl = 1.f / o4[qg][r];
            size_t row = (size_t)(b * S_LEN + qbase + wave * 32 + qg * 16 + quad * 4 + r);
            float* op = O + row * D_MODEL + h * DH + n16;
            op[0]  = o[qg][0][r] * rl;
            op[16] = o[qg][1][r] * rl;
            op[32] = o[qg][2][r] * rl;
            op[48] = o[qg][3][r] * rl;
        }
    }
}

extern "C" void kernel_launch(void* const* d_in, const int* in_sizes, int n_in,
                              void* d_out, int out_size, void* d_ws, size_t ws_size,
                              hipStream_t stream) {
    const float* Q = (const float*)d_in[0];
    const float* K = (const float*)d_in[1];
    const float* V = (const float*)d_in[2];
    const int*   M = (const int*)d_in[3];
    float*       O = (float*)d_out;

    const size_t NEL = (size_t)2 * S_LEN * D_MODEL;            // 4,194,304
    const size_t VT_BYTES = NEL * sizeof(unsigned short);      // 8 MB
    const size_t KB_BYTES = NEL * sizeof(unsigned short);      // 8 MB
    const size_t MB_BYTES = (size_t)2 * S_LEN * 32 * 8;        // 1 MB

    if (ws_size >= VT_BYTES + KB_BYTES + MB_BYTES) {           // 17 MB: full precompute
        unsigned short* VT = (unsigned short*)d_ws;
        unsigned short* KB = (unsigned short*)((char*)d_ws + VT_BYTES);
        unsigned long long* Mb = (unsigned long long*)((char*)d_ws + VT_BYTES + KB_BYTES);
        hipLaunchKernelGGL(cvt_fused, dim3(3072), dim3(256), 0, stream, V, M, K, VT, Mb, KB);
        hipLaunchKernelGGL(mha_fwd_v13, dim3(512), dim3(256), 0, stream,
                           Q, K, KB, VT, Mb, O, 1);
    } else {                                                   // 9 MB: inline K convert
        unsigned short* VT = (unsigned short*)d_ws;
        unsigned long long* Mb = (unsigned long long*)((char*)d_ws + VT_BYTES);
        hipLaunchKernelGGL(cvt_fused, dim3(2048), dim3(256), 0, stream, V, M, K, VT, Mb, (unsigned short*)0);
        hipLaunchKernelGGL(mha_fwd_v13, dim3(512), dim3(256), 0, stream,
                           Q, K, (const unsigned short*)0, VT, Mb, O, 0);
    }
}

// Round 11
// 171.120 us; speedup vs baseline: 1.2540x; 1.1018x over previous
//
#include <hip/hip_runtime.h>

#define S_LEN 2048
#define D_MODEL 1024
#define DH 64      // head dim
#define BQ 128     // q rows per block (32 per wave)
#define BK 128     // keys per k-tile
#define LDK 72     // padded LDS row stride for K (u16 elems)
#define LDV 136    // padded LDS row stride for V (u16 elems)
#define ZSCALE 0.18033688f   // 0.125 * log2(e) — folded into Q fragments

using short8 = __attribute__((ext_vector_type(8))) short;
using s4v    = __attribute__((ext_vector_type(4))) short;
using f32x4  = __attribute__((ext_vector_type(4))) float;
using u32x4  = __attribute__((ext_vector_type(4))) unsigned int;

#define BMM(a, b, c) __builtin_amdgcn_mfma_f32_16x16x32_bf16((a), (b), (c), 0, 0, 0)

__device__ __forceinline__ unsigned short f2bf(float x) {
    union { float f; unsigned int u; } c; c.f = x;
    unsigned int u = c.u;
    u += 0x7fffu + ((u >> 16) & 1u);   // RNE
    return (unsigned short)(u >> 16);
}

// ---- fused converter (verified) ----
__global__ __launch_bounds__(256) void cvt_fused(const float* __restrict__ V,
                                                 const int* __restrict__ M,
                                                 const float* __restrict__ K,
                                                 unsigned short* __restrict__ VT,
                                                 unsigned long long* __restrict__ Mb,
                                                 unsigned short* __restrict__ KB) {
    const int blk = blockIdx.x;
    const int tid = threadIdx.x;
    if (blk < 1024) {
        __shared__ float tsF[64][65];
        const int b  = blk >> 9;
        const int h  = (blk >> 5) & 15;
        const int s0 = (blk & 31) * 64;
        #pragma unroll
        for (int it = 0; it < 2; ++it) {
            int seg = tid + it * 256;
            int s = seg >> 3, d8 = (seg & 7) << 3;
            const float* p = V + (size_t)(b * S_LEN + s0 + s) * D_MODEL + h * DH + d8;
            f32x4 a = *(const f32x4*)p;
            f32x4 c = *(const f32x4*)(p + 4);
            #pragma unroll
            for (int j = 0; j < 4; ++j) { tsF[s][d8 + j] = a[j]; tsF[s][d8 + 4 + j] = c[j]; }
        }
        __syncthreads();
        #pragma unroll
        for (int it = 0; it < 2; ++it) {
            int seg = tid + it * 256;
            int d = seg >> 3, s8 = (seg & 7) << 3;
            short8 w;
            #pragma unroll
            for (int j = 0; j < 8; ++j) w[j] = (short)f2bf(tsF[s8 + j][d]);
            *(short8*)(VT + ((size_t)((b * 16 + h) * 64 + d)) * S_LEN + s0 + s8) = w;
        }
    } else if (blk < 2048) {
        const int pb   = blk - 1024;
        const int wave = tid >> 6, lane = tid & 63;
        const int row  = pb * 4 + wave;
        const int* mp  = M + (size_t)row * S_LEN;
        #pragma unroll 4
        for (int it = 0; it < 32; ++it) {
            int m = mp[it * 64 + lane];
            unsigned long long bal = __ballot(m != 0);
            if (lane == 0) Mb[(size_t)row * 32 + it] = bal;
        }
    } else {
        size_t base = (size_t)(blk - 2048) * 4096;
        #pragma unroll
        for (int it = 0; it < 4; ++it) {
            size_t i = base + ((size_t)(it * 256 + tid)) * 4;
            f32x4 a = *(const f32x4*)(K + i);
            s4v w;
            #pragma unroll
            for (int j = 0; j < 4; ++j) w[j] = (short)f2bf(a[j]);
            *(s4v*)(KB + i) = w;
        }
    }
}

// ---- main kernel v14 = v11 (67.5 us verified) with ONE change:
//      the compute region interleaves PV[kc] between QK ct pairs
//      (QK0,QK1,QK2, PV0, QK3,QK4, PV1, QK5,QK6, PV2, QK7, PV3) so PV's
//      ds_read/MFMA fill QK's exp2/perm VALU stalls.  Zero extra registers,
//      zero LDS change, zero barrier change — Af[kc] dies at its PVKC.
__global__ __launch_bounds__(256) void mha_fwd_v14(
    const float* __restrict__ Q,
    const float* __restrict__ K,             // f32 (used when KB == 0)
    const unsigned short* __restrict__ KB,   // bf16 preconverted (may be null)
    const unsigned short* __restrict__ VT,   // bf16 pre-transposed [d][s]
    const unsigned long long* __restrict__ Mb, // packed mask u64, 32/row
    float* __restrict__ O,
    int kbf)
{
    __shared__ alignas(16) unsigned short Ks[BK][LDK];
    __shared__ alignas(16) unsigned short Vt[DH][LDV];

    // XCD-chunked swizzle: nwg=512, 8 XCDs -> each XCD gets 64 contiguous blk
    const int blk0 = blockIdx.x;
    const int blk  = ((blk0 & 7) << 6) | (blk0 >> 3);

    const int b   = blk >> 8;
    const int h   = (blk >> 4) & 15;
    const int qbase = (blk & 15) * BQ;
    const int bh  = b * 16 + h;

    const int tid  = threadIdx.x;
    const int wave = tid >> 6;
    const int lane = tid & 63;
    const int n16  = lane & 15;
    const int quad = lane >> 4;
    const int bq   = quad << 3;          // mask half-word shift

    // K staging: 256 thr cover 32 rows x 64 cols per round (4 rounds), sigma rows
    const int srow = tid >> 3, sc8 = (tid & 7) << 3;
    const int prow = (((srow >> 2) & 1) << 4) | (((srow >> 3) & 3) << 2) | (srow & 3);
    // V staging: 256 thr cover 16 rows x 128 cols per round (4 rounds)
    const int vrow = tid >> 4, vc8 = (tid & 15) << 3;

    // Q fragments (B operand), PRE-SCALED by ZSCALE
    short8 qf[2][2];
    #pragma unroll
    for (int qg = 0; qg < 2; ++qg) {
        const size_t qoff = (size_t)(b * S_LEN + qbase + wave * 32 + qg * 16 + n16) * D_MODEL
                          + h * DH + quad * 8;
        f32x4 a0 = *(const f32x4*)(Q + qoff);
        f32x4 a1 = *(const f32x4*)(Q + qoff + 4);
        f32x4 a2 = *(const f32x4*)(Q + qoff + 32);
        f32x4 a3 = *(const f32x4*)(Q + qoff + 36);
        short8 q0, q1;
        #pragma unroll
        for (int j = 0; j < 4; ++j) {
            q0[j] = (short)f2bf(a0[j] * ZSCALE); q0[4 + j] = (short)f2bf(a1[j] * ZSCALE);
            q1[j] = (short)f2bf(a2[j] * ZSCALE); q1[4 + j] = (short)f2bf(a3[j] * ZSCALE);
        }
        qf[qg][0] = q0; qf[qg][1] = q1;
    }

    const short8 ones = {0x3F80,0x3F80,0x3F80,0x3F80,0x3F80,0x3F80,0x3F80,0x3F80}; // bf16 1.0

    f32x4 o[2][4], o4[2];
    #pragma unroll
    for (int qg = 0; qg < 2; ++qg) {
        #pragma unroll
        for (int dg = 0; dg < 4; ++dg) o[qg][dg] = f32x4{0.f,0.f,0.f,0.f};
        o4[qg] = f32x4{0.f,0.f,0.f,0.f};
    }

    const unsigned long long* mrow[2];
    #pragma unroll
    for (int qg = 0; qg < 2; ++qg)
        mrow[qg] = Mb + (size_t)(b * S_LEN + qbase + wave * 32 + qg * 16 + n16) * 32;

    const size_t kbase = (size_t)(b * S_LEN) * D_MODEL + h * DH;
    const size_t vbase = (size_t)(bh * 64) * S_LEN;

    // ---- prologue: prefetch tile 0 into regs ----
    short8 ka[4], va[4];
    unsigned long long mw[2][2];
    if (kbf) {
        #pragma unroll
        for (int i = 0; i < 4; ++i)
            ka[i] = *(const short8*)(KB + kbase + (size_t)(i * 32 + srow) * D_MODEL + sc8);
    } else {
        #pragma unroll
        for (int i = 0; i < 4; ++i) {
            const float* kp = K + kbase + (size_t)(i * 32 + srow) * D_MODEL + sc8;
            f32x4 p0 = *(const f32x4*)kp, p1 = *(const f32x4*)(kp + 4);
            short8 w;
            #pragma unroll
            for (int j = 0; j < 4; ++j) { w[j] = (short)f2bf(p0[j]); w[4 + j] = (short)f2bf(p1[j]); }
            ka[i] = w;
        }
    }
    #pragma unroll
    for (int i = 0; i < 4; ++i)   // VT is [d][s]: tile offset on the COLUMN
        va[i] = *(const short8*)(VT + vbase + (size_t)(vrow + 16 * i) * S_LEN + vc8);
    #pragma unroll
    for (int qg = 0; qg < 2; ++qg) { mw[qg][0] = mrow[qg][0]; mw[qg][1] = mrow[qg][1]; }

    for (int kb = 0; kb < S_LEN; kb += BK) {
        // barrier 1: all waves done READING prev tile; raw (no vmcnt drain)
        __builtin_amdgcn_s_barrier();
        __builtin_amdgcn_sched_barrier(0);

        // stage tile
        #pragma unroll
        for (int i = 0; i < 4; ++i) {
            *(short8*)&Ks[prow + 32 * i][sc8] = ka[i];
            *(short8*)&Vt[vrow + 16 * i][vc8] = va[i];
        }

        // issue next tile's loads — consumed by NEXT iteration's ds_writes
        const int kn = kb + BK;
        const bool more = kn < S_LEN;
        short8 nka[4], nva[4];
        unsigned long long nmw[2][2];
        if (more) {
            if (kbf) {
                #pragma unroll
                for (int i = 0; i < 4; ++i)
                    nka[i] = *(const short8*)(KB + kbase + (size_t)(kn + i * 32 + srow) * D_MODEL + sc8);
            } else {
                #pragma unroll
                for (int i = 0; i < 4; ++i) {
                    const float* kp = K + kbase + (size_t)(kn + i * 32 + srow) * D_MODEL + sc8;
                    f32x4 p0 = *(const f32x4*)kp, p1 = *(const f32x4*)(kp + 4);
                    short8 w;
                    #pragma unroll
                    for (int j = 0; j < 4; ++j) { w[j] = (short)f2bf(p0[j]); w[4 + j] = (short)f2bf(p1[j]); }
                    nka[i] = w;
                }
            }
            #pragma unroll
            for (int i = 0; i < 4; ++i)
                nva[i] = *(const short8*)(VT + vbase + (size_t)(vrow + 16 * i) * S_LEN + kn + vc8);
            const int wi = kn >> 6;
            #pragma unroll
            for (int qg = 0; qg < 2; ++qg) { nmw[qg][0] = mrow[qg][wi]; nmw[qg][1] = mrow[qg][wi + 1]; }
        }

        // barrier 2: my LDS writes committed (lgkm only), then all waves sync
        asm volatile("s_waitcnt lgkmcnt(0)" ::: "memory");
        __builtin_amdgcn_s_barrier();
        __builtin_amdgcn_sched_barrier(0);

        // mask half-words, pre-shifted by quad
        unsigned int am[2][4];
        #pragma unroll
        for (int qg = 0; qg < 2; ++qg) {
            am[qg][0] = ((unsigned int)mw[qg][0]) >> bq;
            am[qg][1] = ((unsigned int)(mw[qg][0] >> 32)) >> bq;
            am[qg][2] = ((unsigned int)mw[qg][1]) >> bq;
            am[qg][3] = ((unsigned int)(mw[qg][1] >> 32)) >> bq;
        }

        // ---- interleaved compute: QK ct-pairs feeding PV kc, in one region ----
        u32x4 Af[2][4];   // [qg][kc]
        auto QKCT = [&](int ct) {
            short8 kf0 = *(const short8*)&Ks[ct * 16 + n16][     quad * 8];
            short8 kf1 = *(const short8*)&Ks[ct * 16 + n16][32 + quad * 8];
            f32x4 sA = {0.f,0.f,0.f,0.f}, sB = sA;
            sA = BMM(kf0, qf[0][0], sA); sA = BMM(kf1, qf[0][1], sA);
            sB = BMM(kf0, qf[1][0], sB); sB = BMM(kf1, qf[1][1], sB);
            unsigned int puA[4], puB[4];
            #pragma unroll
            for (int r = 0; r < 4; ++r) {
                puA[r] = __float_as_uint(__builtin_amdgcn_exp2f(sA[r]));
                puB[r] = __float_as_uint(__builtin_amdgcn_exp2f(sB[r]));
            }
            const int sel = ct >> 1, sb = (ct & 1) * 4, kc = ct >> 1, ub = (ct & 1) * 2;
            unsigned int nibA = (am[0][sel] >> sb) & 0xFu;
            unsigned int nibB = (am[1][sel] >> sb) & 0xFu;
            unsigned int m8A = ((nibA * 0x00204081u) & 0x01010101u) * 0xFFu;
            unsigned int m8B = ((nibB * 0x00204081u) & 0x01010101u) * 0xFFu;
            Af[0][kc][ub + 0] = __builtin_amdgcn_perm(puA[1], puA[0], 0x07060302u)
                              & __builtin_amdgcn_perm(0u, m8A, 0x01010000u);
            Af[0][kc][ub + 1] = __builtin_amdgcn_perm(puA[3], puA[2], 0x07060302u)
                              & __builtin_amdgcn_perm(0u, m8A, 0x03030202u);
            Af[1][kc][ub + 0] = __builtin_amdgcn_perm(puB[1], puB[0], 0x07060302u)
                              & __builtin_amdgcn_perm(0u, m8B, 0x01010000u);
            Af[1][kc][ub + 1] = __builtin_amdgcn_perm(puB[3], puB[2], 0x07060302u)
                              & __builtin_amdgcn_perm(0u, m8B, 0x03030202u);
        };
        auto PVKC = [&](int kc) {
            short8 v0 = *(const short8*)&Vt[      n16][kc * 32 + quad * 8];
            short8 v1 = *(const short8*)&Vt[16 + n16][kc * 32 + quad * 8];
            short8 v2 = *(const short8*)&Vt[32 + n16][kc * 32 + quad * 8];
            short8 v3 = *(const short8*)&Vt[48 + n16][kc * 32 + quad * 8];
            union { u32x4 u; short8 s; } c0, c1;
            c0.u = Af[0][kc]; c1.u = Af[1][kc];
            o[0][0] = BMM(c0.s, v0, o[0][0]); o[0][1] = BMM(c0.s, v1, o[0][1]);
            o[0][2] = BMM(c0.s, v2, o[0][2]); o[0][3] = BMM(c0.s, v3, o[0][3]);
            o4[0]   = BMM(c0.s, ones, o4[0]);
            o[1][0] = BMM(c1.s, v0, o[1][0]); o[1][1] = BMM(c1.s, v1, o[1][1]);
            o[1][2] = BMM(c1.s, v2, o[1][2]); o[1][3] = BMM(c1.s, v3, o[1][3]);
            o4[1]   = BMM(c1.s, ones, o4[1]);
        };

        __builtin_amdgcn_s_setprio(1);
        QKCT(0); QKCT(1); QKCT(2);
        PVKC(0);
        QKCT(3); QKCT(4);
        PVKC(1);
        QKCT(5); QKCT(6);
        PVKC(2);
        QKCT(7);
        PVKC(3);
        __builtin_amdgcn_s_setprio(0);

        if (more) {
            #pragma unroll
            for (int i = 0; i < 4; ++i) { ka[i] = nka[i]; va[i] = nva[i]; }
            #pragma unroll
            for (int qg = 0; qg < 2; ++qg) { mw[qg][0] = nmw[qg][0]; mw[qg][1] = nmw[qg][1]; }
        }
    }

    // epilogue: normalize by MFMA row sums, store f32 (row=quad*4+r, col=n16)
    #pragma unroll
    for (int qg = 0; qg < 2; ++qg) {
        #pragma unroll
        for (int r = 0; r < 4; ++r) {
            float rl = 1.f / o4[qg][r];
            size_t row = (size_t)(b * S_LEN + qbase + wave * 32 + qg * 16 + quad * 4 + r);
            float* op = O + row * D_MODEL + h * DH + n16;
            op[0]  = o[qg][0][r] * rl;
            op[16] = o[qg][1][r] * rl;
            op[32] = o[qg][2][r] * rl;
            op[48] = o[qg][3][r] * rl;
        }
    }
}

extern "C" void kernel_launch(void* const* d_in, const int* in_sizes, int n_in,
                              void* d_out, int out_size, void* d_ws, size_t ws_size,
                              hipStream_t stream) {
    const float* Q = (const float*)d_in[0];
    const float* K = (const float*)d_in[1];
    const float* V = (const float*)d_in[2];
    const int*   M = (const int*)d_in[3];
    float*       O = (float*)d_out;

    const size_t NEL = (size_t)2 * S_LEN * D_MODEL;            // 4,194,304
    const size_t VT_BYTES = NEL * sizeof(unsigned short);      // 8 MB
    const size_t KB_BYTES = NEL * sizeof(unsigned short);      // 8 MB
    const size_t MB_BYTES = (size_t)2 * S_LEN * 32 * 8;        // 1 MB

    if (ws_size >= VT_BYTES + KB_BYTES + MB_BYTES) {           // 17 MB: full precompute
        unsigned short* VT = (unsigned short*)d_ws;
        unsigned short* KB = (unsigned short*)((char*)d_ws + VT_BYTES);
        unsigned long long* Mb = (unsigned long long*)((char*)d_ws + VT_BYTES + KB_BYTES);
        hipLaunchKernelGGL(cvt_fused, dim3(3072), dim3(256), 0, stream, V, M, K, VT, Mb, KB);
        hipLaunchKernelGGL(mha_fwd_v14, dim3(512), dim3(256), 0, stream,
                           Q, K, KB, VT, Mb, O, 1);
    } else {                                                   // 9 MB: inline K convert
        unsigned short* VT = (unsigned short*)d_ws;
        unsigned long long* Mb = (unsigned long long*)((char*)d_ws + VT_BYTES);
        hipLaunchKernelGGL(cvt_fused, dim3(2048), dim3(256), 0, stream, V, M, K, VT, Mb, (unsigned short*)0);
        hipLaunchKernelGGL(mha_fwd_v14, dim3(512), dim3(256), 0, stream,
                           Q, K, (const unsigned short*)0, VT, Mb, O, 0);
    }
}

// Round 12
// 170.207 us; speedup vs baseline: 1.2607x; 1.0054x over previous
//
#include <hip/hip_runtime.h>

#define S_LEN 2048
#define D_MODEL 1024
#define DH 64      // head dim
#define BQ 128     // q rows per block (32 per wave)
#define BK 128     // keys per k-tile
#define ZSCALE 0.18033688f   // 0.125 * log2(e) — folded into Q fragments

using short8 = __attribute__((ext_vector_type(8))) short;
using s4v    = __attribute__((ext_vector_type(4))) short;
using f32x4  = __attribute__((ext_vector_type(4))) float;
using u32x4  = __attribute__((ext_vector_type(4))) unsigned int;

#define BMM(a, b, c) __builtin_amdgcn_mfma_f32_16x16x32_bf16((a), (b), (c), 0, 0, 0)

__device__ __forceinline__ unsigned short f2bf(float x) {
    union { float f; unsigned int u; } c; c.f = x;
    unsigned int u = c.u;
    u += 0x7fffu + ((u >> 16) & 1u);   // RNE
    return (unsigned short)(u >> 16);
}

// ---- fused converter (verified) ----
__global__ __launch_bounds__(256) void cvt_fused(const float* __restrict__ V,
                                                 const int* __restrict__ M,
                                                 const float* __restrict__ K,
                                                 unsigned short* __restrict__ VT,
                                                 unsigned long long* __restrict__ Mb,
                                                 unsigned short* __restrict__ KB) {
    const int blk = blockIdx.x;
    const int tid = threadIdx.x;
    if (blk < 1024) {
        __shared__ float tsF[64][65];
        const int b  = blk >> 9;
        const int h  = (blk >> 5) & 15;
        const int s0 = (blk & 31) * 64;
        #pragma unroll
        for (int it = 0; it < 2; ++it) {
            int seg = tid + it * 256;
            int s = seg >> 3, d8 = (seg & 7) << 3;
            const float* p = V + (size_t)(b * S_LEN + s0 + s) * D_MODEL + h * DH + d8;
            f32x4 a = *(const f32x4*)p;
            f32x4 c = *(const f32x4*)(p + 4);
            #pragma unroll
            for (int j = 0; j < 4; ++j) { tsF[s][d8 + j] = a[j]; tsF[s][d8 + 4 + j] = c[j]; }
        }
        __syncthreads();
        #pragma unroll
        for (int it = 0; it < 2; ++it) {
            int seg = tid + it * 256;
            int d = seg >> 3, s8 = (seg & 7) << 3;
            short8 w;
            #pragma unroll
            for (int j = 0; j < 8; ++j) w[j] = (short)f2bf(tsF[s8 + j][d]);
            *(short8*)(VT + ((size_t)((b * 16 + h) * 64 + d)) * S_LEN + s0 + s8) = w;
        }
    } else if (blk < 2048) {
        const int pb   = blk - 1024;
        const int wave = tid >> 6, lane = tid & 63;
        const int row  = pb * 4 + wave;
        const int* mp  = M + (size_t)row * S_LEN;
        #pragma unroll 4
        for (int it = 0; it < 32; ++it) {
            int m = mp[it * 64 + lane];
            unsigned long long bal = __ballot(m != 0);
            if (lane == 0) Mb[(size_t)row * 32 + it] = bal;
        }
    } else {
        size_t base = (size_t)(blk - 2048) * 4096;
        #pragma unroll
        for (int it = 0; it < 4; ++it) {
            size_t i = base + ((size_t)(it * 256 + tid)) * 4;
            f32x4 a = *(const f32x4*)(K + i);
            s4v w;
            #pragma unroll
            for (int j = 0; j < 4; ++j) w[j] = (short)f2bf(a[j]);
            *(s4v*)(KB + i) = w;
        }
    }
}

// ---- main kernel v15 = v14 (59.5 us verified) with:
//  (a) unpadded LDS rows + 16B-granule XOR swizzle (phys = logical ^ (row &
//      (ngran-1)), same formula on write and read) -> every K/V LDS access is
//      exactly 8 dw/bank (balanced minimum); kills the 4.2M conflict cycles
//  (b) finer QK/PV interleave: PV[kc] fires right after its two QK cts
//  (c) mask-word expansion hoisted off the post-barrier critical path
__global__ __launch_bounds__(256) void mha_fwd_v15(
    const float* __restrict__ Q,
    const float* __restrict__ K,             // f32 (used when KB == 0)
    const unsigned short* __restrict__ KB,   // bf16 preconverted (may be null)
    const unsigned short* __restrict__ VT,   // bf16 pre-transposed [d][s]
    const unsigned long long* __restrict__ Mb, // packed mask u64, 32/row
    float* __restrict__ O,
    int kbf)
{
    __shared__ alignas(16) unsigned short Ks[BK][64];   // 16 KB, stride 32 dw
    __shared__ alignas(16) unsigned short Vt[DH][128];  // 16 KB, stride 64 dw

    // XCD-chunked swizzle: nwg=512, 8 XCDs -> each XCD gets 64 contiguous blk
    const int blk0 = blockIdx.x;
    const int blk  = ((blk0 & 7) << 6) | (blk0 >> 3);

    const int b   = blk >> 8;
    const int h   = (blk >> 4) & 15;
    const int qbase = (blk & 15) * BQ;
    const int bh  = b * 16 + h;

    const int tid  = threadIdx.x;
    const int wave = tid >> 6;
    const int lane = tid & 63;
    const int n16  = lane & 15;
    const int quad = lane >> 4;
    const int bq   = quad << 3;          // mask half-word shift
    const int n7   = n16 & 7;

    // K staging: 256 thr cover 32 rows x 64 cols per round (4 rounds), sigma rows
    const int srow = tid >> 3;
    const int prow = (((srow >> 2) & 1) << 4) | (((srow >> 3) & 3) << 2) | (srow & 3);
    // V staging: 256 thr cover 16 rows x 128 cols per round (4 rounds)
    const int vrow = tid >> 4;

    // LDS XOR-swizzle columns (16B granules; phys = logical ^ (row & (ng-1)))
    const int kwcol = (((tid & 7) ^ (prow & 7)) << 3);    // K write col (row&7 = prow&7)
    const int vwcol = (((tid & 15) ^ vrow) << 3);         // V write col (row&15 = vrow)
    const int krc0  = ((quad ^ n7) << 3);                 // K read col, logical g=quad
    const int krc1  = krc0 ^ 32;                          // logical g=quad+4 (XOR bit2)
    int vrc[4];                                           // V read col per kc
    #pragma unroll
    for (int kc = 0; kc < 4; ++kc) vrc[kc] = (((kc * 4 + quad) ^ n16) << 3);

    // Q fragments (B operand), PRE-SCALED by ZSCALE
    short8 qf[2][2];
    #pragma unroll
    for (int qg = 0; qg < 2; ++qg) {
        const size_t qoff = (size_t)(b * S_LEN + qbase + wave * 32 + qg * 16 + n16) * D_MODEL
                          + h * DH + quad * 8;
        f32x4 a0 = *(const f32x4*)(Q + qoff);
        f32x4 a1 = *(const f32x4*)(Q + qoff + 4);
        f32x4 a2 = *(const f32x4*)(Q + qoff + 32);
        f32x4 a3 = *(const f32x4*)(Q + qoff + 36);
        short8 q0, q1;
        #pragma unroll
        for (int j = 0; j < 4; ++j) {
            q0[j] = (short)f2bf(a0[j] * ZSCALE); q0[4 + j] = (short)f2bf(a1[j] * ZSCALE);
            q1[j] = (short)f2bf(a2[j] * ZSCALE); q1[4 + j] = (short)f2bf(a3[j] * ZSCALE);
        }
        qf[qg][0] = q0; qf[qg][1] = q1;
    }

    const short8 ones = {0x3F80,0x3F80,0x3F80,0x3F80,0x3F80,0x3F80,0x3F80,0x3F80}; // bf16 1.0

    f32x4 o[2][4], o4[2];
    #pragma unroll
    for (int qg = 0; qg < 2; ++qg) {
        #pragma unroll
        for (int dg = 0; dg < 4; ++dg) o[qg][dg] = f32x4{0.f,0.f,0.f,0.f};
        o4[qg] = f32x4{0.f,0.f,0.f,0.f};
    }

    const unsigned long long* mrow[2];
    #pragma unroll
    for (int qg = 0; qg < 2; ++qg)
        mrow[qg] = Mb + (size_t)(b * S_LEN + qbase + wave * 32 + qg * 16 + n16) * 32;

    const size_t kbase = (size_t)(b * S_LEN) * D_MODEL + h * DH;
    const size_t vbase = (size_t)(bh * 64) * S_LEN;

    // ---- prologue: prefetch tile 0 into regs ----
    short8 ka[4], va[4];
    unsigned long long mw[2][2];
    if (kbf) {
        #pragma unroll
        for (int i = 0; i < 4; ++i)
            ka[i] = *(const short8*)(KB + kbase + (size_t)(i * 32 + srow) * D_MODEL + ((tid & 7) << 3));
    } else {
        #pragma unroll
        for (int i = 0; i < 4; ++i) {
            const float* kp = K + kbase + (size_t)(i * 32 + srow) * D_MODEL + ((tid & 7) << 3);
            f32x4 p0 = *(const f32x4*)kp, p1 = *(const f32x4*)(kp + 4);
            short8 w;
            #pragma unroll
            for (int j = 0; j < 4; ++j) { w[j] = (short)f2bf(p0[j]); w[4 + j] = (short)f2bf(p1[j]); }
            ka[i] = w;
        }
    }
    #pragma unroll
    for (int i = 0; i < 4; ++i)   // VT is [d][s]: tile offset on the COLUMN
        va[i] = *(const short8*)(VT + vbase + (size_t)(vrow + 16 * i) * S_LEN + ((tid & 15) << 3));
    #pragma unroll
    for (int qg = 0; qg < 2; ++qg) { mw[qg][0] = mrow[qg][0]; mw[qg][1] = mrow[qg][1]; }

    for (int kb = 0; kb < S_LEN; kb += BK) {
        // barrier 1: all waves done READING prev tile; raw (no vmcnt drain)
        __builtin_amdgcn_s_barrier();
        __builtin_amdgcn_sched_barrier(0);

        // stage tile (swizzled columns; sigma-permuted K rows)
        #pragma unroll
        for (int i = 0; i < 4; ++i) {
            *(short8*)&Ks[prow + 32 * i][kwcol] = ka[i];
            *(short8*)&Vt[vrow + 16 * i][vwcol] = va[i];
        }

        // issue next tile's loads — consumed by NEXT iteration's ds_writes
        const int kn = kb + BK;
        const bool more = kn < S_LEN;
        short8 nka[4], nva[4];
        unsigned long long nmw[2][2];
        if (more) {
            if (kbf) {
                #pragma unroll
                for (int i = 0; i < 4; ++i)
                    nka[i] = *(const short8*)(KB + kbase + (size_t)(kn + i * 32 + srow) * D_MODEL + ((tid & 7) << 3));
            } else {
                #pragma unroll
                for (int i = 0; i < 4; ++i) {
                    const float* kp = K + kbase + (size_t)(kn + i * 32 + srow) * D_MODEL + ((tid & 7) << 3);
                    f32x4 p0 = *(const f32x4*)kp, p1 = *(const f32x4*)(kp + 4);
                    short8 w;
                    #pragma unroll
                    for (int j = 0; j < 4; ++j) { w[j] = (short)f2bf(p0[j]); w[4 + j] = (short)f2bf(p1[j]); }
                    nka[i] = w;
                }
            }
            #pragma unroll
            for (int i = 0; i < 4; ++i)
                nva[i] = *(const short8*)(VT + vbase + (size_t)(vrow + 16 * i) * S_LEN + kn + ((tid & 15) << 3));
            const int wi = kn >> 6;
            #pragma unroll
            for (int qg = 0; qg < 2; ++qg) { nmw[qg][0] = mrow[qg][wi]; nmw[qg][1] = mrow[qg][wi + 1]; }
        }

        // mask half-words (register-only; hoisted off the post-barrier path)
        unsigned int am[2][4];
        #pragma unroll
        for (int qg = 0; qg < 2; ++qg) {
            am[qg][0] = ((unsigned int)mw[qg][0]) >> bq;
            am[qg][1] = ((unsigned int)(mw[qg][0] >> 32)) >> bq;
            am[qg][2] = ((unsigned int)mw[qg][1]) >> bq;
            am[qg][3] = ((unsigned int)(mw[qg][1] >> 32)) >> bq;
        }

        // barrier 2: my LDS writes committed (lgkm only), then all waves sync
        asm volatile("s_waitcnt lgkmcnt(0)" ::: "memory");
        __builtin_amdgcn_s_barrier();
        __builtin_amdgcn_sched_barrier(0);

        // ---- interleaved compute: PV[kc] fires right after its two QK cts ----
        u32x4 Af[2][4];   // [qg][kc]
        auto QKCT = [&](int ct) {
            short8 kf0 = *(const short8*)&Ks[ct * 16 + n16][krc0];
            short8 kf1 = *(const short8*)&Ks[ct * 16 + n16][krc1];
            f32x4 sA = {0.f,0.f,0.f,0.f}, sB = sA;
            sA = BMM(kf0, qf[0][0], sA); sA = BMM(kf1, qf[0][1], sA);
            sB = BMM(kf0, qf[1][0], sB); sB = BMM(kf1, qf[1][1], sB);
            unsigned int puA[4], puB[4];
            #pragma unroll
            for (int r = 0; r < 4; ++r) {
                puA[r] = __float_as_uint(__builtin_amdgcn_exp2f(sA[r]));
                puB[r] = __float_as_uint(__builtin_amdgcn_exp2f(sB[r]));
            }
            const int sel = ct >> 1, sb = (ct & 1) * 4, kc = ct >> 1, ub = (ct & 1) * 2;
            unsigned int nibA = (am[0][sel] >> sb) & 0xFu;
            unsigned int nibB = (am[1][sel] >> sb) & 0xFu;
            unsigned int m8A = ((nibA * 0x00204081u) & 0x01010101u) * 0xFFu;
            unsigned int m8B = ((nibB * 0x00204081u) & 0x01010101u) * 0xFFu;
            Af[0][kc][ub + 0] = __builtin_amdgcn_perm(puA[1], puA[0], 0x07060302u)
                              & __builtin_amdgcn_perm(0u, m8A, 0x01010000u);
            Af[0][kc][ub + 1] = __builtin_amdgcn_perm(puA[3], puA[2], 0x07060302u)
                              & __builtin_amdgcn_perm(0u, m8A, 0x03030202u);
            Af[1][kc][ub + 0] = __builtin_amdgcn_perm(puB[1], puB[0], 0x07060302u)
                              & __builtin_amdgcn_perm(0u, m8B, 0x01010000u);
            Af[1][kc][ub + 1] = __builtin_amdgcn_perm(puB[3], puB[2], 0x07060302u)
                              & __builtin_amdgcn_perm(0u, m8B, 0x03030202u);
        };
        auto PVKC = [&](int kc) {
            short8 v0 = *(const short8*)&Vt[      n16][vrc[kc]];
            short8 v1 = *(const short8*)&Vt[16 + n16][vrc[kc]];
            short8 v2 = *(const short8*)&Vt[32 + n16][vrc[kc]];
            short8 v3 = *(const short8*)&Vt[48 + n16][vrc[kc]];
            union { u32x4 u; short8 s; } c0, c1;
            c0.u = Af[0][kc]; c1.u = Af[1][kc];
            o[0][0] = BMM(c0.s, v0, o[0][0]); o[0][1] = BMM(c0.s, v1, o[0][1]);
            o[0][2] = BMM(c0.s, v2, o[0][2]); o[0][3] = BMM(c0.s, v3, o[0][3]);
            o4[0]   = BMM(c0.s, ones, o4[0]);
            o[1][0] = BMM(c1.s, v0, o[1][0]); o[1][1] = BMM(c1.s, v1, o[1][1]);
            o[1][2] = BMM(c1.s, v2, o[1][2]); o[1][3] = BMM(c1.s, v3, o[1][3]);
            o4[1]   = BMM(c1.s, ones, o4[1]);
        };

        __builtin_amdgcn_s_setprio(1);
        QKCT(0); QKCT(1);
        PVKC(0);
        QKCT(2); QKCT(3);
        PVKC(1);
        QKCT(4); QKCT(5);
        PVKC(2);
        QKCT(6); QKCT(7);
        PVKC(3);
        __builtin_amdgcn_s_setprio(0);

        if (more) {
            #pragma unroll
            for (int i = 0; i < 4; ++i) { ka[i] = nka[i]; va[i] = nva[i]; }
            #pragma unroll
            for (int qg = 0; qg < 2; ++qg) { mw[qg][0] = nmw[qg][0]; mw[qg][1] = nmw[qg][1]; }
        }
    }

    // epilogue: normalize by MFMA row sums, store f32 (row=quad*4+r, col=n16)
    #pragma unroll
    for (int qg = 0; qg < 2; ++qg) {
        #pragma unroll
        for (int r = 0; r < 4; ++r) {
            float rl = 1.f / o4[qg][r];
            size_t row = (size_t)(b * S_LEN + qbase + wave * 32 + qg * 16 + quad * 4 + r);
            float* op = O + row * D_MODEL + h * DH + n16;
            op[0]  = o[qg][0][r] * rl;
            op[16] = o[qg][1][r] * rl;
            op[32] = o[qg][2][r] * rl;
            op[48] = o[qg][3][r] * rl;
        }
    }
}

extern "C" void kernel_launch(void* const* d_in, const int* in_sizes, int n_in,
                              void* d_out, int out_size, void* d_ws, size_t ws_size,
                              hipStream_t stream) {
    const float* Q = (const float*)d_in[0];
    const float* K = (const float*)d_in[1];
    const float* V = (const float*)d_in[2];
    const int*   M = (const int*)d_in[3];
    float*       O = (float*)d_out;

    const size_t NEL = (size_t)2 * S_LEN * D_MODEL;            // 4,194,304
    const size_t VT_BYTES = NEL * sizeof(unsigned short);      // 8 MB
    const size_t KB_BYTES = NEL * sizeof(unsigned short);      // 8 MB
    const size_t MB_BYTES = (size_t)2 * S_LEN * 32 * 8;        // 1 MB

    if (ws_size >= VT_BYTES + KB_BYTES + MB_BYTES) {           // 17 MB: full precompute
        unsigned short* VT = (unsigned short*)d_ws;
        unsigned short* KB = (unsigned short*)((char*)d_ws + VT_BYTES);
        unsigned long long* Mb = (unsigned long long*)((char*)d_ws + VT_BYTES + KB_BYTES);
        hipLaunchKernelGGL(cvt_fused, dim3(3072), dim3(256), 0, stream, V, M, K, VT, Mb, KB);
        hipLaunchKernelGGL(mha_fwd_v15, dim3(512), dim3(256), 0, stream,
                           Q, K, KB, VT, Mb, O, 1);
    } else {                                                   // 9 MB: inline K convert
        unsigned short* VT = (unsigned short*)d_ws;
        unsigned long long* Mb = (unsigned long long*)((char*)d_ws + VT_BYTES);
        hipLaunchKernelGGL(cvt_fused, dim3(2048), dim3(256), 0, stream, V, M, K, VT, Mb, (unsigned short*)0);
        hipLaunchKernelGGL(mha_fwd_v15, dim3(512), dim3(256), 0, stream,
                           Q, K, (const unsigned short*)0, VT, Mb, O, 0);
    }
}